// Round 1
// baseline (285.331 us; speedup 1.0000x reference)
//
#include <hip/hip_runtime.h>
#include <math.h>

// Problem constants (B=4, H=W=128, C=256, 2x2 pool, VALID)
#define HP   64
#define WPOL 64
#define C4   64                      // 256 channels / 4 (float4 groups)
#define NT4  (4 * HP * WPOL * C4)    // 1,048,576 float4 groups per output tensor
#define NELEM ((size_t)NT4 * 4)      // 4,194,304 floats per output tensor

// ---- float atomic min/max via int-representation monotone trick ----
__device__ __forceinline__ void atomicMaxF(float* addr, float val) {
    if (val >= 0.0f) atomicMax((int*)addr, __float_as_int(val));
    else             atomicMin((unsigned int*)addr, __float_as_uint(val));
}
__device__ __forceinline__ void atomicMinF(float* addr, float val) {
    if (val >= 0.0f) atomicMin((int*)addr, __float_as_int(val));
    else             atomicMax((unsigned int*)addr, __float_as_uint(val));
}

// Seed the two scalar outputs with l / u so the main kernel's atomics
// fold the final max(l, l_t) / min(u, u_t) clamp for free.
__global__ void init_kernel(const float* __restrict__ l_in,
                            const float* __restrict__ u_in,
                            float* __restrict__ out) {
    out[4 * NELEM]     = l_in[0];
    out[4 * NELEM + 1] = u_in[0];
}

__device__ __forceinline__ float fc(const float4& v, int i) {
    return i == 0 ? v.x : (i == 1 ? v.y : (i == 2 ? v.z : v.w));
}

__global__ __launch_bounds__(256) void maxpool_kernel(
    const float4* __restrict__ x,  const float4* __restrict__ bias,
    const float4* __restrict__ a,  const float4* __restrict__ bt,
    float* __restrict__ out)
{
    const int g  = blockIdx.x * 256 + threadIdx.x;   // [0, NT4)
    const int c4 = g & 63;
    const int wp = (g >> 6) & 63;
    const int hp = (g >> 12) & 63;
    const int bb = g >> 18;
    // input float4 index of window corner (ph=0, pw=0)
    const int base = ((bb * 128 + 2 * hp) * 128 + 2 * wp) * 64 + c4;
    // window order (ph,pw) = (0,0),(0,1),(1,0),(1,1) in float4 units
    const int offs[4] = {0, 64, 8192, 8256};

    float4 X[4], Bv[4], A[4], Bt[4];
#pragma unroll
    for (int j = 0; j < 4; ++j) X[j]  = x[base + offs[j]];
#pragma unroll
    for (int j = 0; j < 4; ++j) Bv[j] = bias[base + offs[j]];
#pragma unroll
    for (int j = 0; j < 4; ++j) A[j]  = a[base + offs[j]];
#pragma unroll
    for (int j = 0; j < 4; ++j) Bt[j] = bt[base + offs[j]];

    float lmax = -INFINITY, umin = INFINITY;
    float rx[4], rb[4], ra[4], rc[4];

#pragma unroll
    for (int c = 0; c < 4; ++c) {
        float xw[4], bw[4], aw[4], cw[4];
#pragma unroll
        for (int j = 0; j < 4; ++j) {
            xw[j] = fc(X[j], c);  bw[j] = fc(Bv[j], c);
            aw[j] = fc(A[j], c);  cw[j] = fc(Bt[j], c);
        }
        // first-occurrence argmax (strict >) with fused gather of the other 3
        float sx = xw[0], sb = bw[0], sa = aw[0], sc = cw[0];
#pragma unroll
        for (int j = 1; j < 4; ++j) {
            bool gt = xw[j] > sx;
            sx = gt ? xw[j] : sx;
            sb = gt ? bw[j] : sb;
            sa = gt ? aw[j] : sa;
            sc = gt ? cw[j] : sc;
        }
        rx[c] = sx; rb[c] = sb; ra[c] = sa; rc[c] = sc;

        // truncated interval over the 4 window entries
#pragma unroll
        for (int j = 0; j < 4; ++j) {
            float tb  = cw[j] - sc;
            float nom = -((aw[j] - sa) + (bw[j] - sb));
            float q   = nom / tb;            // consumed only when tb != 0
            if (tb > 0.0f)      umin = fminf(umin, q);
            else if (tb < 0.0f) lmax = fmaxf(lmax, q);
        }
    }

    // coalesced float4 stores, outputs concatenated [x | bias | a | b | l | u]
    ((float4*)out)[g]                    = make_float4(rx[0], rx[1], rx[2], rx[3]);
    ((float4*)(out + NELEM))[g]          = make_float4(rb[0], rb[1], rb[2], rb[3]);
    ((float4*)(out + 2 * NELEM))[g]      = make_float4(ra[0], ra[1], ra[2], ra[3]);
    ((float4*)(out + 3 * NELEM))[g]      = make_float4(rc[0], rc[1], rc[2], rc[3]);

    // ---- block reduction of (lmax, umin) ----
#pragma unroll
    for (int s = 32; s; s >>= 1) {
        lmax = fmaxf(lmax, __shfl_down(lmax, s, 64));
        umin = fminf(umin, __shfl_down(umin, s, 64));
    }
    __shared__ float sl[4], su[4];
    const int wave = threadIdx.x >> 6;
    if ((threadIdx.x & 63) == 0) { sl[wave] = lmax; su[wave] = umin; }
    __syncthreads();
    if (threadIdx.x == 0) {
        float ll = fmaxf(fmaxf(sl[0], sl[1]), fmaxf(sl[2], sl[3]));
        float uu = fminf(fminf(su[0], su[1]), fminf(su[2], su[3]));
        atomicMaxF(&out[4 * NELEM],     ll);
        atomicMinF(&out[4 * NELEM + 1], uu);
    }
}

extern "C" void kernel_launch(void* const* d_in, const int* in_sizes, int n_in,
                              void* d_out, int out_size, void* d_ws, size_t ws_size,
                              hipStream_t stream) {
    const float4* x    = (const float4*)d_in[0];
    const float4* bias = (const float4*)d_in[1];
    const float4* a    = (const float4*)d_in[2];
    const float4* bt   = (const float4*)d_in[3];
    const float*  l_in = (const float*)d_in[4];
    const float*  u_in = (const float*)d_in[5];
    float* out = (float*)d_out;

    init_kernel<<<1, 1, 0, stream>>>(l_in, u_in, out);
    maxpool_kernel<<<NT4 / 256, 256, 0, stream>>>(x, bias, a, bt, out);
}

// Round 2
// 282.145 us; speedup vs baseline: 1.0113x; 1.0113x over previous
//
#include <hip/hip_runtime.h>
#include <math.h>

// Problem constants (B=4, H=W=128, C=256, 2x2 pool, VALID)
#define HP   64
#define WPOL 64
#define C4   64                      // 256 channels / 4 (float4 groups)
#define NT4  (4 * HP * WPOL * C4)    // 1,048,576 float4 groups per output tensor
#define NELEM ((size_t)NT4 * 4)      // 4,194,304 floats per output tensor

// ---- float atomic min/max via int-representation monotone trick ----
__device__ __forceinline__ void atomicMaxF(float* addr, float val) {
    if (val >= 0.0f) atomicMax((int*)addr, __float_as_int(val));
    else             atomicMin((unsigned int*)addr, __float_as_uint(val));
}
__device__ __forceinline__ void atomicMinF(float* addr, float val) {
    if (val >= 0.0f) atomicMin((int*)addr, __float_as_int(val));
    else             atomicMax((unsigned int*)addr, __float_as_uint(val));
}

// Seed the two scalar outputs with l / u so the main kernel's atomics
// fold the final max(l, l_t) / min(u, u_t) clamp for free.
__global__ void init_kernel(const float* __restrict__ l_in,
                            const float* __restrict__ u_in,
                            float* __restrict__ out) {
    out[4 * NELEM]     = l_in[0];
    out[4 * NELEM + 1] = u_in[0];
}

__device__ __forceinline__ float fc(const float4& v, int i) {
    return i == 0 ? v.x : (i == 1 ? v.y : (i == 2 ? v.z : v.w));
}

__global__ __launch_bounds__(256) void maxpool_kernel(
    const float4* __restrict__ x,  const float4* __restrict__ bias,
    const float4* __restrict__ a,  const float4* __restrict__ bt,
    float* __restrict__ out)
{
    const int g  = blockIdx.x * 256 + threadIdx.x;   // [0, NT4)
    const int c4 = g & 63;
    const int wp = (g >> 6) & 63;
    const int hp = (g >> 12) & 63;
    const int bb = g >> 18;
    // input float4 index of window corner (ph=0, pw=0)
    const int base = ((bb * 128 + 2 * hp) * 128 + 2 * wp) * 64 + c4;

    // window order (ph,pw) = (0,0),(0,1),(1,0),(1,1) in float4 units:
    // +0, +64 (one w step), +8192 (one h step = 128*64), +8256
    float4 X0  = x[base],        X1  = x[base + 64],
           X2  = x[base + 8192], X3  = x[base + 8256];
    float4 Bv0 = bias[base],        Bv1 = bias[base + 64],
           Bv2 = bias[base + 8192], Bv3 = bias[base + 8256];
    float4 A0  = a[base],        A1  = a[base + 64],
           A2  = a[base + 8192], A3  = a[base + 8256];
    float4 Bt0 = bt[base],        Bt1 = bt[base + 64],
           Bt2 = bt[base + 8192], Bt3 = bt[base + 8256];
    // Pin all 16 loads above any consumer: one load cluster, one wait phase
    // (vs the previous build's 4 dependent load->wait->use phases at VGPR=36).
    __builtin_amdgcn_sched_barrier(0);

    const float4 X[4]  = {X0, X1, X2, X3};
    const float4 Bv[4] = {Bv0, Bv1, Bv2, Bv3};
    const float4 A[4]  = {A0, A1, A2, A3};
    const float4 Bt[4] = {Bt0, Bt1, Bt2, Bt3};

    float lmax = -INFINITY, umin = INFINITY;
    float rx[4], rb[4], ra[4], rc[4];

#pragma unroll
    for (int c = 0; c < 4; ++c) {
        float xw[4], bw[4], aw[4], cw[4];
#pragma unroll
        for (int j = 0; j < 4; ++j) {
            xw[j] = fc(X[j], c);  bw[j] = fc(Bv[j], c);
            aw[j] = fc(A[j], c);  cw[j] = fc(Bt[j], c);
        }
        // first-occurrence argmax (strict >) with fused gather of the other 3
        float sx = xw[0], sb = bw[0], sa = aw[0], sc = cw[0];
#pragma unroll
        for (int j = 1; j < 4; ++j) {
            bool gt = xw[j] > sx;
            sx = gt ? xw[j] : sx;
            sb = gt ? bw[j] : sb;
            sa = gt ? aw[j] : sa;
            sc = gt ? cw[j] : sc;
        }
        rx[c] = sx; rb[c] = sb; ra[c] = sa; rc[c] = sc;

        // truncated interval over the 4 window entries
#pragma unroll
        for (int j = 0; j < 4; ++j) {
            float tb  = cw[j] - sc;
            float nom = -((aw[j] - sa) + (bw[j] - sb));
            float q   = nom / tb;            // consumed only when tb != 0
            if (tb > 0.0f)      umin = fminf(umin, q);
            else if (tb < 0.0f) lmax = fmaxf(lmax, q);
        }
    }

    // coalesced float4 stores, outputs concatenated [x | bias | a | b | l | u]
    // issued BEFORE the reduction tail so store latency overlaps the shuffles
    ((float4*)out)[g]                    = make_float4(rx[0], rx[1], rx[2], rx[3]);
    ((float4*)(out + NELEM))[g]          = make_float4(rb[0], rb[1], rb[2], rb[3]);
    ((float4*)(out + 2 * NELEM))[g]      = make_float4(ra[0], ra[1], ra[2], ra[3]);
    ((float4*)(out + 3 * NELEM))[g]      = make_float4(rc[0], rc[1], rc[2], rc[3]);

    // ---- block reduction of (lmax, umin) ----
#pragma unroll
    for (int s = 32; s; s >>= 1) {
        lmax = fmaxf(lmax, __shfl_down(lmax, s, 64));
        umin = fminf(umin, __shfl_down(umin, s, 64));
    }
    __shared__ float sl[4], su[4];
    const int wave = threadIdx.x >> 6;
    if ((threadIdx.x & 63) == 0) { sl[wave] = lmax; su[wave] = umin; }
    __syncthreads();
    if (threadIdx.x == 0) {
        float ll = fmaxf(fmaxf(sl[0], sl[1]), fmaxf(sl[2], sl[3]));
        float uu = fminf(fminf(su[0], su[1]), fminf(su[2], su[3]));
        atomicMaxF(&out[4 * NELEM],     ll);
        atomicMinF(&out[4 * NELEM + 1], uu);
    }
}

extern "C" void kernel_launch(void* const* d_in, const int* in_sizes, int n_in,
                              void* d_out, int out_size, void* d_ws, size_t ws_size,
                              hipStream_t stream) {
    const float4* x    = (const float4*)d_in[0];
    const float4* bias = (const float4*)d_in[1];
    const float4* a    = (const float4*)d_in[2];
    const float4* bt   = (const float4*)d_in[3];
    const float*  l_in = (const float*)d_in[4];
    const float*  u_in = (const float*)d_in[5];
    float* out = (float*)d_out;

    init_kernel<<<1, 1, 0, stream>>>(l_in, u_in, out);
    maxpool_kernel<<<NT4 / 256, 256, 0, stream>>>(x, bias, a, bt, out);
}